// Round 2
// baseline (4486.798 us; speedup 1.0000x reference)
//
#include <hip/hip_runtime.h>
#include <math.h>

#ifndef M_PI
#define M_PI 3.14159265358979323846
#endif

#define BD 256
#define NB 16
#define DIM 1024
#define SMAX 288
#define NSTEPS 32
#define NPROPS 512
#define NTOK (16 * 256 * 1024)

__device__ __forceinline__ double wred_sum(double v) {
#pragma unroll
    for (int o = 32; o > 0; o >>= 1) v += __shfl_down(v, o, 64);
    return v;
}
__device__ __forceinline__ double wred_max(double v) {
#pragma unroll
    for (int o = 32; o > 0; o >>= 1) { double w = __shfl_down(v, o, 64); if (w > v) v = w; }
    return v;
}
__device__ double block_sum(double v, double* sc) {
    v = wred_sum(v);
    int tid = threadIdx.x;
    if ((tid & 63) == 0) sc[tid >> 6] = v;
    __syncthreads();
    double r = sc[0] + sc[1] + sc[2] + sc[3];
    __syncthreads();
    return r;
}
__device__ double block_max(double v, double* sc) {
    v = wred_max(v);
    int tid = threadIdx.x;
    if ((tid & 63) == 0) sc[tid >> 6] = v;
    __syncthreads();
    double r = fmax(fmax(sc[0], sc[1]), fmax(sc[2], sc[3]));
    __syncthreads();
    return r;
}

// ---- canonicalize tokens: handles harness passing int32 OR raw int64 ----
// Detection: view buffer as int32; if odd words over the first 256 tokens are
// all zero, layout is little-endian int64 (high words of 0/1 values). With
// real int32 0/1 data, 256 odd words all-zero has P ~= 2^-256.
__global__ __launch_bounds__(256) void k_tok_convert(const int* __restrict__ tok32,
                                                     signed char* __restrict__ tokc) {
    __shared__ int flag;
    int tid = threadIdx.x;
    if (tid == 0) {
        int nz = 0;
        for (int i = 1; i < 512; i += 2) nz |= tok32[i];
        flag = nz;
    }
    __syncthreads();
    bool is64 = (flag == 0);
#pragma unroll
    for (int it = 0; it < 4; ++it) {
        size_t idx = (size_t)blockIdx.x * 1024 + it * BD + tid;
        int v = is64 ? tok32[2 * idx] : tok32[idx];
        tokc[idx] = (signed char)v;
    }
}

// ---- prefix: per-token LN stats (tokens are 0/1) ----
__global__ __launch_bounds__(256) void k_prefix_stats(const signed char* __restrict__ tokc,
                                                      double* __restrict__ mu, double* __restrict__ rs) {
    __shared__ double sc[4];
    int T = blockIdx.x, tid = threadIdx.x;
    const signed char* row = tokc + (size_t)T * DIM;
    double s = 0;
    for (int i = tid; i < DIM; i += BD) s += (double)row[i];
    s = block_sum(s, sc);
    double m = s * (1.0 / 1024.0);
    double ss = 0;
    for (int i = tid; i < DIM; i += BD) { double d = (double)row[i] - m; ss += d * d; }
    ss = block_sum(ss, sc);
    if (tid == 0) { mu[T] = m; rs[T] = 1.0 / sqrt(ss * (1.0 / 1024.0) + 1e-5); }
}

__global__ __launch_bounds__(256) void k_init_xl(const signed char* __restrict__ tokc, double* __restrict__ xl) {
    int b = blockIdx.x, tid = threadIdx.x;
    for (int i = tid; i < DIM; i += BD)
        xl[b * DIM + i] = (double)tokc[((size_t)b * 256 + 255) * DIM + i];
}

// ---- prefix K,V GEMM: [4096 tokens x 1024] @ Wqkv[:,1024:3072], fp64 ----
// 16(T) x 64(j) tiles: 256 threads x 4 acc = 1024 outputs per block.
__global__ __launch_bounds__(256) void k_prefix(const signed char* __restrict__ tokc,
        const double* __restrict__ mu, const double* __restrict__ rs,
        const float* __restrict__ Wqkv, const float* __restrict__ bqkv,
        const float* __restrict__ g1, const float* __restrict__ b1,
        double* __restrict__ Kc, double* __restrict__ Vc) {
    __shared__ double Hs[64 * 17];   // [k][t], t-dim padded to 17
    __shared__ float  Ws[64 * 64];   // [k][j]
    int tid = threadIdx.x;
    int tx = tid & 63, ty = tid >> 6;
    int j0 = blockIdx.x * 64;        // kv-col space 0..2047
    int T0 = blockIdx.y * 16;        // token tile
    double acc[4] = {0, 0, 0, 0};
    for (int kc = 0; kc < DIM; kc += 64) {
#pragma unroll
        for (int it = 0; it < 4; ++it) {
            int idx = tid + it * BD;           // 0..1023
            int t = idx & 15, k = idx >> 4;
            int T = T0 + t;
            double x = (double)tokc[(size_t)T * DIM + kc + k];
            Hs[k * 17 + t] = (x - mu[T]) * rs[T] * (double)g1[kc + k] + (double)b1[kc + k];
        }
#pragma unroll
        for (int it = 0; it < 16; ++it) {
            int idx = tid + it * BD;
            int k = idx >> 6, j = idx & 63;
            Ws[k * 64 + j] = Wqkv[(size_t)(kc + k) * 3072 + 1024 + j0 + j];
        }
        __syncthreads();
#pragma unroll 8
        for (int k = 0; k < 64; ++k) {
            double w = (double)Ws[k * 64 + tx];
            acc[0] += Hs[k * 17 + ty * 4 + 0] * w;
            acc[1] += Hs[k * 17 + ty * 4 + 1] * w;
            acc[2] += Hs[k * 17 + ty * 4 + 2] * w;
            acc[3] += Hs[k * 17 + ty * 4 + 3] * w;
        }
        __syncthreads();
    }
    int colg = j0 + tx;
    double bias = (double)bqkv[1024 + colg];
    bool isK = (colg < 1024);
#pragma unroll
    for (int a = 0; a < 4; ++a) {
        int T = T0 + ty * 4 + a;
        int b = T >> 8, pos = T & 255;
        double v = acc[a] + bias;
        if (isK) Kc[((size_t)b * SMAX + pos) * DIM + colg] = v;
        else     Vc[((size_t)b * SMAX + pos) * DIM + colg - 1024] = v;
    }
}

// ---- LN of last token ----
__global__ __launch_bounds__(256) void k_ln1(const double* __restrict__ xl, const float* __restrict__ g,
                                             const float* __restrict__ bb, double* __restrict__ h1) {
    __shared__ double xs[DIM];
    __shared__ double sc[4];
    int b = blockIdx.x, tid = threadIdx.x;
    for (int i = tid; i < DIM; i += BD) xs[i] = xl[b * DIM + i];
    __syncthreads();
    double s = 0;
    for (int i = tid; i < DIM; i += BD) s += xs[i];
    s = block_sum(s, sc);
    double m = s * (1.0 / 1024.0);
    double ss = 0;
    for (int i = tid; i < DIM; i += BD) { double d = xs[i] - m; ss += d * d; }
    ss = block_sum(ss, sc);
    double r = 1.0 / sqrt(ss * (1.0 / 1024.0) + 1e-5);
    for (int i = tid; i < DIM; i += BD)
        h1[b * DIM + i] = (xs[i] - m) * r * (double)g[i] + (double)bb[i];
}

// ---- batched 16-row matvec: P[ky][b][col] = sum_k A[b][k]*W[k][col] over k-slice ----
__global__ __launch_bounds__(256) void mm16(const double* __restrict__ A, int K,
        const float* __restrict__ W, int ldw, double* __restrict__ P, int ncols) {
    __shared__ double As[16 * 64];
    __shared__ float  Ws[64 * 64];
    int tid = threadIdx.x, tx = tid & 63, ty = tid >> 6;
    int j0 = blockIdx.x * 64;
    int klen = K / gridDim.y;
    int k0 = blockIdx.y * klen;
    double acc[4] = {0, 0, 0, 0};
    for (int kc = 0; kc < klen; kc += 64) {
#pragma unroll
        for (int it = 0; it < 4; ++it) {
            int idx = tid + it * BD;
            int b = idx >> 6, k = idx & 63;
            As[b * 64 + k] = A[(size_t)b * K + k0 + kc + k];
        }
#pragma unroll
        for (int it = 0; it < 16; ++it) {
            int idx = tid + it * BD;
            int k = idx >> 6, j = idx & 63;
            Ws[k * 64 + j] = W[(size_t)(k0 + kc + k) * ldw + j0 + j];
        }
        __syncthreads();
#pragma unroll 8
        for (int k = 0; k < 64; ++k) {
            double w = (double)Ws[k * 64 + tx];
            acc[0] += As[(ty * 4 + 0) * 64 + k] * w;
            acc[1] += As[(ty * 4 + 1) * 64 + k] * w;
            acc[2] += As[(ty * 4 + 2) * 64 + k] * w;
            acc[3] += As[(ty * 4 + 3) * 64 + k] * w;
        }
        __syncthreads();
    }
#pragma unroll
    for (int a = 0; a < 4; ++a)
        P[((size_t)(blockIdx.y * 16 + ty * 4 + a)) * ncols + j0 + tx] = acc[a];
}

// ---- transposed-W variant (W_score is [out, K]) ----
__global__ __launch_bounds__(256) void mm16_t(const double* __restrict__ A, int K,
        const float* __restrict__ Wt, double* __restrict__ P, int ncols) {
    __shared__ double As[16 * 64];
    __shared__ float  Ws[64 * 65];
    int tid = threadIdx.x, tx = tid & 63, ty = tid >> 6;
    int j0 = blockIdx.x * 64;
    int klen = K / gridDim.y;
    int k0 = blockIdx.y * klen;
    double acc[4] = {0, 0, 0, 0};
    for (int kc = 0; kc < klen; kc += 64) {
#pragma unroll
        for (int it = 0; it < 4; ++it) {
            int idx = tid + it * BD;
            int b = idx >> 6, k = idx & 63;
            As[b * 64 + k] = A[(size_t)b * K + k0 + kc + k];
        }
#pragma unroll
        for (int it = 0; it < 16; ++it) {
            int idx = tid + it * BD;
            int j = idx >> 6, k = idx & 63;
            Ws[k * 65 + j] = Wt[(size_t)(j0 + j) * K + k0 + kc + k];
        }
        __syncthreads();
#pragma unroll 8
        for (int k = 0; k < 64; ++k) {
            double w = (double)Ws[k * 65 + tx];
            acc[0] += As[(ty * 4 + 0) * 64 + k] * w;
            acc[1] += As[(ty * 4 + 1) * 64 + k] * w;
            acc[2] += As[(ty * 4 + 2) * 64 + k] * w;
            acc[3] += As[(ty * 4 + 3) * 64 + k] * w;
        }
        __syncthreads();
    }
#pragma unroll
    for (int a = 0; a < 4; ++a)
        P[((size_t)(blockIdx.y * 16 + ty * 4 + a)) * ncols + j0 + tx] = acc[a];
}

// ---- combine qkv partials: q buffer + append k,v to cache ----
__global__ __launch_bounds__(256) void k_combine_kv(const double* __restrict__ P1, const float* __restrict__ bqkv,
        double* __restrict__ q, double* __restrict__ Kc, double* __restrict__ Vc, int pos) {
    int b = blockIdx.x;
    int col = blockIdx.y * BD + threadIdx.x;  // 0..3071
    double s = (double)bqkv[col];
    for (int ks = 0; ks < 8; ++ks) s += P1[((size_t)(ks * 16 + b)) * 3072 + col];
    if (col < 1024)      q[b * DIM + col] = s;
    else if (col < 2048) Kc[((size_t)b * SMAX + pos) * DIM + col - 1024] = s;
    else                 Vc[((size_t)b * SMAX + pos) * DIM + col - 2048] = s;
}

// ---- last-row attention scores ----
__global__ __launch_bounds__(256) void k_scores(const double* __restrict__ q, const double* __restrict__ Kc,
                                                double* __restrict__ sco, int S) {
    __shared__ double qs[DIM];
    int b = blockIdx.x, tid = threadIdx.x;
    int lane = tid & 63, w = tid >> 6;
    for (int i = tid; i < DIM; i += BD) qs[i] = q[b * DIM + i];
    __syncthreads();
    int base = blockIdx.y * 32 + w * 8;
    for (int r = 0; r < 8; ++r) {
        int pos = base + r;
        if (pos >= S) break;
        const double* kp = Kc + ((size_t)b * SMAX + pos) * DIM;
        double acc = 0;
#pragma unroll
        for (int ii = 0; ii < 16; ++ii) acc += qs[lane + 64 * ii] * kp[lane + 64 * ii];
        acc = wred_sum(acc);
        if (lane == 0) sco[b * SMAX + pos] = acc * 0.03125;  // /sqrt(1024)
    }
}

// ---- softmax + P@V ----
__global__ __launch_bounds__(256) void k_attnout(const double* __restrict__ sco, const double* __restrict__ Vc,
                                                 double* __restrict__ ao, int S) {
    __shared__ double ps[SMAX];
    __shared__ double sc[4];
    int b = blockIdx.x, tid = threadIdx.x;
    double lm = -1e300;
    for (int i = tid; i < S; i += BD) { double v = sco[b * SMAX + i]; ps[i] = v; if (v > lm) lm = v; }
    __syncthreads();
    double mx = block_max(lm, sc);
    double le = 0;
    for (int i = tid; i < S; i += BD) { double e = exp(ps[i] - mx); ps[i] = e; le += e; }
    double den = block_sum(le, sc);
    int d = blockIdx.y * BD + tid;
    double a0 = 0, a1 = 0, a2 = 0, a3 = 0;
    int pos = 0;
    for (; pos + 4 <= S; pos += 4) {
        a0 += ps[pos + 0] * Vc[((size_t)b * SMAX + pos + 0) * DIM + d];
        a1 += ps[pos + 1] * Vc[((size_t)b * SMAX + pos + 1) * DIM + d];
        a2 += ps[pos + 2] * Vc[((size_t)b * SMAX + pos + 2) * DIM + d];
        a3 += ps[pos + 3] * Vc[((size_t)b * SMAX + pos + 3) * DIM + d];
    }
    for (; pos < S; ++pos) a0 += ps[pos] * Vc[((size_t)b * SMAX + pos) * DIM + d];
    ao[b * DIM + d] = ((a0 + a1) + (a2 + a3)) / den;
}

// ---- x2 = xl + aproj + bias; LN2 -> h2 ----
__global__ __launch_bounds__(256) void k_ln2(const double* __restrict__ xl, const double* __restrict__ P2,
        const float* __restrict__ bap, const float* __restrict__ g2, const float* __restrict__ b2,
        double* __restrict__ x2, double* __restrict__ h2) {
    __shared__ double xs[DIM];
    __shared__ double sc[4];
    int b = blockIdx.x, tid = threadIdx.x;
    for (int i = tid; i < DIM; i += BD) {
        double s = xl[b * DIM + i] + (double)bap[i];
        for (int ks = 0; ks < 8; ++ks) s += P2[((size_t)(ks * 16 + b)) * DIM + i];
        xs[i] = s; x2[b * DIM + i] = s;
    }
    __syncthreads();
    double s = 0;
    for (int i = tid; i < DIM; i += BD) s += xs[i];
    s = block_sum(s, sc);
    double m = s * (1.0 / 1024.0);
    double ss = 0;
    for (int i = tid; i < DIM; i += BD) { double d = xs[i] - m; ss += d * d; }
    ss = block_sum(ss, sc);
    double r = 1.0 / sqrt(ss * (1.0 / 1024.0) + 1e-5);
    for (int i = tid; i < DIM; i += BD)
        h2[b * DIM + i] = (xs[i] - m) * r * (double)g2[i] + (double)b2[i];
}

// ---- m = gelu_new(fc + bias) ----
__global__ __launch_bounds__(256) void k_gelu(const double* __restrict__ P3, const float* __restrict__ bfc,
                                              double* __restrict__ m) {
    int b = blockIdx.x;
    int i = blockIdx.y * BD + threadIdx.x;  // 0..4095
    double u = (double)bfc[i];
    for (int ks = 0; ks < 8; ++ks) u += P3[((size_t)(ks * 16 + b)) * 4096 + i];
    double c = sqrt(2.0 / M_PI);
    double inner = c * (u + 0.044715 * u * u * u);
    m[(size_t)b * 4096 + i] = 0.5 * u * (1.0 + tanh(inner));
}

// ---- x3 = x2 + mproj + bias; LNf -> hf ----
__global__ __launch_bounds__(256) void k_lnf(const double* __restrict__ x2, const double* __restrict__ P4,
        const float* __restrict__ bmp, const float* __restrict__ gf, const float* __restrict__ bf,
        double* __restrict__ hf) {
    __shared__ double xs[DIM];
    __shared__ double sc[4];
    int b = blockIdx.x, tid = threadIdx.x;
    for (int i = tid; i < DIM; i += BD) {
        double s = x2[b * DIM + i] + (double)bmp[i];
        for (int ks = 0; ks < 32; ++ks) s += P4[((size_t)(ks * 16 + b)) * DIM + i];
        xs[i] = s;
    }
    __syncthreads();
    double s = 0;
    for (int i = tid; i < DIM; i += BD) s += xs[i];
    s = block_sum(s, sc);
    double m = s * (1.0 / 1024.0);
    double ss = 0;
    for (int i = tid; i < DIM; i += BD) { double d = xs[i] - m; ss += d * d; }
    ss = block_sum(ss, sc);
    double r = 1.0 / sqrt(ss * (1.0 / 1024.0) + 1e-5);
    for (int i = tid; i < DIM; i += BD)
        hf[b * DIM + i] = (xs[i] - m) * r * (double)gf[i] + (double)bf[i];
}

// ---- logits out + threshold -> new last token ----
__global__ __launch_bounds__(256) void k_final(const double* __restrict__ P5, float* __restrict__ out,
                                               double* __restrict__ xl, int t) {
    int b = blockIdx.x, tid = threadIdx.x;
    for (int p = tid; p < NPROPS; p += BD) {
        double lg = 0;
        for (int ks = 0; ks < 8; ++ks) lg += P5[((size_t)(ks * 16 + b)) * NPROPS + p];
        out[((size_t)b * NSTEPS + t) * NPROPS + p] = (float)lg;
        xl[b * DIM + p] = 0.0;
        xl[b * DIM + 512 + p] = (lg > 0.0) ? 1.0 : 0.0;
    }
}

extern "C" void kernel_launch(void* const* d_in, const int* in_sizes, int n_in,
                              void* d_out, int out_size, void* d_ws, size_t ws_size,
                              hipStream_t stream) {
    const int*   tok  = (const int*)d_in[0];
    const float* Wqkv = (const float*)d_in[1];
    const float* bqkv = (const float*)d_in[2];
    const float* Wap  = (const float*)d_in[3];
    const float* bap  = (const float*)d_in[4];
    const float* g1   = (const float*)d_in[5];
    const float* b1   = (const float*)d_in[6];
    const float* g2   = (const float*)d_in[7];
    const float* b2   = (const float*)d_in[8];
    const float* Wfc  = (const float*)d_in[9];
    const float* bfc  = (const float*)d_in[10];
    const float* Wmp  = (const float*)d_in[11];
    const float* bmp  = (const float*)d_in[12];
    const float* gf   = (const float*)d_in[13];
    const float* bf   = (const float*)d_in[14];
    const float* Wsc  = (const float*)d_in[15];
    float* out = (float*)d_out;

    char* w = (char*)d_ws;
    size_t off = 0;
    auto alloc = [&](size_t bytes) -> void* {
        void* p = (void*)(w + off);
        off += (bytes + 255) & ~(size_t)255;
        return p;
    };
    double*      Kc   = (double*)alloc((size_t)NB * SMAX * DIM * 8);
    double*      Vc   = (double*)alloc((size_t)NB * SMAX * DIM * 8);
    double*      mu   = (double*)alloc(4096 * 8);
    double*      rs   = (double*)alloc(4096 * 8);
    double*      xl   = (double*)alloc((size_t)NB * DIM * 8);
    double*      h1   = (double*)alloc((size_t)NB * DIM * 8);
    double*      q    = (double*)alloc((size_t)NB * DIM * 8);
    double*      sco  = (double*)alloc((size_t)NB * SMAX * 8);
    double*      ao   = (double*)alloc((size_t)NB * DIM * 8);
    double*      x2   = (double*)alloc((size_t)NB * DIM * 8);
    double*      h2   = (double*)alloc((size_t)NB * DIM * 8);
    double*      m    = (double*)alloc((size_t)NB * 4096 * 8);
    double*      hf   = (double*)alloc((size_t)NB * DIM * 8);
    double*      P1   = (double*)alloc((size_t)8 * NB * 3072 * 8);
    double*      P2   = (double*)alloc((size_t)8 * NB * 1024 * 8);
    double*      P3   = (double*)alloc((size_t)8 * NB * 4096 * 8);
    double*      P4   = (double*)alloc((size_t)32 * NB * 1024 * 8);
    double*      P5   = (double*)alloc((size_t)8 * NB * 512 * 8);
    signed char* tokc = (signed char*)alloc((size_t)NTOK);
    if (off > ws_size) return;  // fail visibly (output stays poisoned)

    k_tok_convert<<<4096, BD, 0, stream>>>(tok, tokc);
    k_prefix_stats<<<4096, BD, 0, stream>>>(tokc, mu, rs);
    k_init_xl<<<NB, BD, 0, stream>>>(tokc, xl);
    k_prefix<<<dim3(32, 256), BD, 0, stream>>>(tokc, mu, rs, Wqkv, bqkv, g1, b1, Kc, Vc);

    for (int t = 0; t < NSTEPS; ++t) {
        int S = 256 + t, pos = 255 + t;
        k_ln1<<<NB, BD, 0, stream>>>(xl, g1, b1, h1);
        mm16<<<dim3(48, 8), BD, 0, stream>>>(h1, 1024, Wqkv, 3072, P1, 3072);
        k_combine_kv<<<dim3(NB, 12), BD, 0, stream>>>(P1, bqkv, q, Kc, Vc, pos);
        k_scores<<<dim3(NB, 9), BD, 0, stream>>>(q, Kc, sco, S);
        k_attnout<<<dim3(NB, 4), BD, 0, stream>>>(sco, Vc, ao, S);
        mm16<<<dim3(16, 8), BD, 0, stream>>>(ao, 1024, Wap, 1024, P2, 1024);
        k_ln2<<<NB, BD, 0, stream>>>(xl, P2, bap, g2, b2, x2, h2);
        mm16<<<dim3(64, 8), BD, 0, stream>>>(h2, 1024, Wfc, 4096, P3, 4096);
        k_gelu<<<dim3(NB, 16), BD, 0, stream>>>(P3, bfc, m);
        mm16<<<dim3(16, 32), BD, 0, stream>>>(m, 4096, Wmp, 1024, P4, 1024);
        k_lnf<<<NB, BD, 0, stream>>>(x2, P4, bmp, gf, bf, hf);
        mm16_t<<<dim3(8, 8), BD, 0, stream>>>(hf, 1024, Wsc, P5, 512);
        k_final<<<NB, BD, 0, stream>>>(P5, out, xl, t);
    }
}